// Round 1
// baseline (346.595 us; speedup 1.0000x reference)
//
#include <hip/hip_runtime.h>

// Haar 3D wavelet: x [B,C,T,H,W] f32 -> out [B, 8*C, Tp, Hp, Wp] f32
// B=2 C=3 T=33 H=512 W=512 ; Tp=17 Hp=256 Wp=256 ; SCALE=0.3536
// Memory-bound: ~207 MB read + ~214 MB write. Each thread: 4 output pixels,
// all 8 sub-bands, via 3-stage butterfly (w, h, t).

constexpr int B_  = 2;
constexpr int C_  = 3;
constexpr int T_  = 33;
constexpr int H_  = 512;
constexpr int W_  = 512;
constexpr int Tp_ = 17;
constexpr int Hp_ = 256;
constexpr int Wp_ = 256;
constexpr int KQ_ = Wp_ / 4;            // 64 float4-output chunks per output row
constexpr float SCALE_ = 0.3536f;

constexpr int TOTAL_THREADS = B_ * C_ * Tp_ * Hp_ * KQ_;   // 1,671,168

__global__ __launch_bounds__(256)
void haar3d_kernel(const float* __restrict__ x, float* __restrict__ out) {
    int idx = blockIdx.x * 256 + threadIdx.x;
    if (idx >= TOTAL_THREADS) return;

    // idx = (((bc*Tp + i)*Hp + j)*KQ + kq
    int kq  = idx & (KQ_ - 1);
    int t   = idx >> 6;                 // KQ = 64
    int j   = t & (Hp_ - 1);
    int rem = t >> 8;                   // Hp = 256
    int i   = rem % Tp_;
    int bc  = rem / Tp_;                // b*C + c
    int b   = bc / C_;
    int c   = bc - b * C_;

    // xp = concat(x[:, :, :1], x): xp[2i] = x[max(2i-1,0)], xp[2i+1] = x[2i]
    int t0 = (i == 0) ? 0 : (2 * i - 1);
    int t1 = 2 * i;
    int h0 = 2 * j;
    int w0 = 8 * kq;                    // 8 input floats in w per thread

    const size_t HW = (size_t)H_ * W_;
    const float* xb = x + (size_t)bc * T_ * HW + (size_t)h0 * W_ + w0;

    const float4* r0 = (const float4*)(xb + (size_t)t0 * HW);        // (t0, h0)
    const float4* r1 = (const float4*)(xb + (size_t)t0 * HW + W_);   // (t0, h0+1)
    const float4* r2 = (const float4*)(xb + (size_t)t1 * HW);        // (t1, h0)
    const float4* r3 = (const float4*)(xb + (size_t)t1 * HW + W_);   // (t1, h0+1)

    float4 a0 = r0[0], a1 = r0[1];
    float4 b0 = r1[0], b1 = r1[1];
    float4 c0 = r2[0], c1 = r2[1];
    float4 d0 = r3[0], d1 = r3[1];

    float v0[8] = {a0.x, a0.y, a0.z, a0.w, a1.x, a1.y, a1.z, a1.w};
    float v1[8] = {b0.x, b0.y, b0.z, b0.w, b1.x, b1.y, b1.z, b1.w};
    float v2[8] = {c0.x, c0.y, c0.z, c0.w, c1.x, c1.y, c1.z, c1.w};
    float v3[8] = {d0.x, d0.y, d0.z, d0.w, d1.x, d1.y, d1.z, d1.w};

    float o[8][4];                      // o[s][p]: sub-band s, pixel p

#pragma unroll
    for (int p = 0; p < 4; ++p) {
        // w stage: sum / diff within each (t,h) row
        float s0 = v0[2*p] + v0[2*p+1], q0 = v0[2*p] - v0[2*p+1];   // (t0,h0)
        float s1 = v1[2*p] + v1[2*p+1], q1 = v1[2*p] - v1[2*p+1];   // (t0,h1)
        float s2 = v2[2*p] + v2[2*p+1], q2 = v2[2*p] - v2[2*p+1];   // (t1,h0)
        float s3 = v3[2*p] + v3[2*p+1], q3 = v3[2*p] - v3[2*p+1];   // (t1,h1)
        // h stage
        float hse0 = s0 + s1, hde0 = s0 - s1;   // dt=0: w-sum h-sum / h-diff
        float hsd0 = q0 + q1, hdd0 = q0 - q1;   // dt=0: w-diff h-sum / h-diff
        float hse1 = s2 + s3, hde1 = s2 - s3;   // dt=1
        float hsd1 = q2 + q3, hdd1 = q2 - q3;
        // t stage; s = st*4 + sh*2 + sw (lll,llh,lhl,lhh,hll,hlh,hhl,hhh)
        o[0][p] = (hse0 + hse1) * SCALE_;
        o[1][p] = (hsd0 + hsd1) * SCALE_;
        o[2][p] = (hde0 + hde1) * SCALE_;
        o[3][p] = (hdd0 + hdd1) * SCALE_;
        o[4][p] = (hse0 - hse1) * SCALE_;
        o[5][p] = (hsd0 - hsd1) * SCALE_;
        o[6][p] = (hde0 - hde1) * SCALE_;
        o[7][p] = (hdd0 - hdd1) * SCALE_;
    }

    // out channel = s*C + c ; flat sub-band stride = C*Tp*Hp*Wp
    const size_t HpWp = (size_t)Hp_ * Wp_;
    const size_t SBSTRIDE = (size_t)C_ * Tp_ * HpWp;   // 3,342,336 floats
    size_t obase = ((size_t)(b * 8 * C_ + c) * Tp_ + i) * HpWp
                 + (size_t)j * Wp_ + 4 * (size_t)kq;

#pragma unroll
    for (int s = 0; s < 8; ++s) {
        float4 v = make_float4(o[s][0], o[s][1], o[s][2], o[s][3]);
        *(float4*)(out + obase + (size_t)s * SBSTRIDE) = v;
    }
}

extern "C" void kernel_launch(void* const* d_in, const int* in_sizes, int n_in,
                              void* d_out, int out_size, void* d_ws, size_t ws_size,
                              hipStream_t stream) {
    const float* x = (const float*)d_in[0];
    float* out = (float*)d_out;
    int blocks = TOTAL_THREADS / 256;   // 6528, exact
    haar3d_kernel<<<blocks, 256, 0, stream>>>(x, out);
}

// Round 3
// 340.546 us; speedup vs baseline: 1.0178x; 1.0178x over previous
//
#include <hip/hip_runtime.h>

// Haar 3D wavelet: x [B,C,T,H,W] f32 -> out [B, 8*C, Tp, Hp, Wp] f32
// B=2 C=3 T=33 H=512 W=512 ; Tp=17 Hp=256 Wp=256 ; SCALE=0.3536
// Pure streaming: 207.6 MB read + 213.9 MB write, zero reuse -> nontemporal
// loads AND stores (bypass L2 allocation). 3D grid avoids div-by-17 decode.
// NOTE: __builtin_nontemporal_* needs a NATIVE vector type, not HIP float4.

typedef float v4f __attribute__((ext_vector_type(4)));

constexpr int B_  = 2;
constexpr int C_  = 3;
constexpr int T_  = 33;
constexpr int H_  = 512;
constexpr int W_  = 512;
constexpr int Tp_ = 17;
constexpr int Hp_ = 256;
constexpr int Wp_ = 256;
constexpr int KQ_ = Wp_ / 4;            // 64 float4-output chunks per output row
constexpr float SCALE_ = 0.3536f;

__global__ __launch_bounds__(256)
void haar3d_kernel(const float* __restrict__ x, float* __restrict__ out) {
    // grid: x = (Hp/4) blocks of 256 threads covering (j, kq); y = i; z = bc
    int tid = threadIdx.x;
    int kq  = tid & (KQ_ - 1);              // 0..63
    int j   = (blockIdx.x << 2) + (tid >> 6);  // 4 rows per block
    int i   = blockIdx.y;
    int bc  = blockIdx.z;                   // b*C + c
    int b   = bc / C_;
    int c   = bc - b * C_;

    // xp = concat(x[:, :, :1], x): xp[2i] = x[max(2i-1,0)], xp[2i+1] = x[2i]
    int t0 = (i == 0) ? 0 : (2 * i - 1);
    int t1 = 2 * i;
    int h0 = 2 * j;
    int w0 = 8 * kq;

    const size_t HW = (size_t)H_ * W_;
    const float* xb = x + (size_t)bc * T_ * HW + (size_t)h0 * W_ + w0;

    const v4f* r0 = (const v4f*)(xb + (size_t)t0 * HW);        // (t0, h0)
    const v4f* r1 = (const v4f*)(xb + (size_t)t0 * HW + W_);   // (t0, h0+1)
    const v4f* r2 = (const v4f*)(xb + (size_t)t1 * HW);        // (t1, h0)
    const v4f* r3 = (const v4f*)(xb + (size_t)t1 * HW + W_);   // (t1, h0+1)

    v4f a0 = __builtin_nontemporal_load(r0);
    v4f a1 = __builtin_nontemporal_load(r0 + 1);
    v4f b0 = __builtin_nontemporal_load(r1);
    v4f b1 = __builtin_nontemporal_load(r1 + 1);
    v4f c0 = __builtin_nontemporal_load(r2);
    v4f c1 = __builtin_nontemporal_load(r2 + 1);
    v4f d0 = __builtin_nontemporal_load(r3);
    v4f d1 = __builtin_nontemporal_load(r3 + 1);

    float v0[8] = {a0.x, a0.y, a0.z, a0.w, a1.x, a1.y, a1.z, a1.w};
    float v1[8] = {b0.x, b0.y, b0.z, b0.w, b1.x, b1.y, b1.z, b1.w};
    float v2[8] = {c0.x, c0.y, c0.z, c0.w, c1.x, c1.y, c1.z, c1.w};
    float v3[8] = {d0.x, d0.y, d0.z, d0.w, d1.x, d1.y, d1.z, d1.w};

    float o[8][4];                      // o[s][p]: sub-band s, pixel p

#pragma unroll
    for (int p = 0; p < 4; ++p) {
        // w stage
        float s0 = v0[2*p] + v0[2*p+1], q0 = v0[2*p] - v0[2*p+1];   // (t0,h0)
        float s1 = v1[2*p] + v1[2*p+1], q1 = v1[2*p] - v1[2*p+1];   // (t0,h1)
        float s2 = v2[2*p] + v2[2*p+1], q2 = v2[2*p] - v2[2*p+1];   // (t1,h0)
        float s3 = v3[2*p] + v3[2*p+1], q3 = v3[2*p] - v3[2*p+1];   // (t1,h1)
        // h stage
        float hse0 = s0 + s1, hde0 = s0 - s1;
        float hsd0 = q0 + q1, hdd0 = q0 - q1;
        float hse1 = s2 + s3, hde1 = s2 - s3;
        float hsd1 = q2 + q3, hdd1 = q2 - q3;
        // t stage; s = st*4 + sh*2 + sw (lll,llh,lhl,lhh,hll,hlh,hhl,hhh)
        o[0][p] = (hse0 + hse1) * SCALE_;
        o[1][p] = (hsd0 + hsd1) * SCALE_;
        o[2][p] = (hde0 + hde1) * SCALE_;
        o[3][p] = (hdd0 + hdd1) * SCALE_;
        o[4][p] = (hse0 - hse1) * SCALE_;
        o[5][p] = (hsd0 - hsd1) * SCALE_;
        o[6][p] = (hde0 - hde1) * SCALE_;
        o[7][p] = (hdd0 - hdd1) * SCALE_;
    }

    // out channel = s*C + c ; sub-band stride = C*Tp*Hp*Wp
    const size_t HpWp = (size_t)Hp_ * Wp_;
    const size_t SBSTRIDE = (size_t)C_ * Tp_ * HpWp;
    float* op = out + ((size_t)(b * 8 * C_ + c) * Tp_ + i) * HpWp
              + (size_t)j * Wp_ + 4 * (size_t)kq;

#pragma unroll
    for (int s = 0; s < 8; ++s) {
        v4f v = {o[s][0], o[s][1], o[s][2], o[s][3]};
        __builtin_nontemporal_store(v, (v4f*)(op + (size_t)s * SBSTRIDE));
    }
}

extern "C" void kernel_launch(void* const* d_in, const int* in_sizes, int n_in,
                              void* d_out, int out_size, void* d_ws, size_t ws_size,
                              hipStream_t stream) {
    const float* x = (const float*)d_in[0];
    float* out = (float*)d_out;
    dim3 grid(Hp_ / 4, Tp_, B_ * C_);   // (64, 17, 6) = 6528 blocks x 256 threads
    haar3d_kernel<<<grid, 256, 0, stream>>>(x, out);
}

// Round 4
// 335.361 us; speedup vs baseline: 1.0335x; 1.0155x over previous
//
#include <hip/hip_runtime.h>

// Haar 3D wavelet: x [B,C,T,H,W] f32 -> out [B, 8*C, Tp, Hp, Wp] f32
// B=2 C=3 T=33 H=512 W=512 ; Tp=17 Hp=256 Wp=256 ; SCALE=0.3536
// Streaming, zero reuse: nontemporal loads+stores.
// R4: fully-contiguous wave loads. Lane i loads float4 = row[4i..4i+3]
// (chunk1, wave covers bytes 0..1023 dense) and row[256+4i..+3] (chunk2,
// bytes 1024..2047 dense). Lane computes pixels {2i,2i+1} and {128+2i,+1};
// stores 8 sub-bands x 2 float2 (512 B dense per wave-store).

typedef float v4f __attribute__((ext_vector_type(4)));
typedef float v2f __attribute__((ext_vector_type(2)));

constexpr int B_  = 2;
constexpr int C_  = 3;
constexpr int T_  = 33;
constexpr int H_  = 512;
constexpr int W_  = 512;
constexpr int Tp_ = 17;
constexpr int Hp_ = 256;
constexpr int Wp_ = 256;
constexpr float SCALE_ = 0.3536f;

__device__ __forceinline__ v4f ntload4(const float* p) {
    return __builtin_nontemporal_load((const v4f*)p);
}

__global__ __launch_bounds__(256)
void haar3d_kernel(const float* __restrict__ x, float* __restrict__ out) {
    int tid  = threadIdx.x;
    int lane = tid & 63;
    int j    = (blockIdx.x << 2) + (tid >> 6);   // 4 output rows per block
    int i    = blockIdx.y;
    int bc   = blockIdx.z;                        // b*C + c
    int b    = (bc >= C_) ? 1 : 0;
    int c    = bc - b * C_;

    // xp = concat(x[:,:,:1], x): xp[2i] = x[max(2i-1,0)], xp[2i+1] = x[2i]
    int t0 = (i == 0) ? 0 : (2 * i - 1);
    int t1 = 2 * i;
    int h0 = 2 * j;

    const size_t HW = (size_t)H_ * W_;
    const float* base = x + (size_t)bc * T_ * HW + (size_t)h0 * W_;
    const float* r00 = base + (size_t)t0 * HW;        // (t0, h0)
    const float* r01 = r00 + W_;                      // (t0, h0+1)
    const float* r10 = base + (size_t)t1 * HW;        // (t1, h0)
    const float* r11 = r10 + W_;                      // (t1, h0+1)

    int w1 = 4 * lane;          // chunk1: input floats w1..w1+3
    int w2 = 256 + 4 * lane;    // chunk2

    v4f A1 = ntload4(r00 + w1), A2 = ntload4(r00 + w2);
    v4f B1 = ntload4(r01 + w1), B2 = ntload4(r01 + w2);
    v4f C1 = ntload4(r10 + w1), C2 = ntload4(r10 + w2);
    v4f D1 = ntload4(r11 + w1), D2 = ntload4(r11 + w2);

    // o[s][chunk][u]: sub-band s, chunk (lo/hi half of row), pixel-in-chunk u
    v2f o[8][2];

#pragma unroll
    for (int q = 0; q < 2; ++q) {
        v4f A = q ? A2 : A1, B = q ? B2 : B1, C = q ? C2 : C1, D = q ? D2 : D1;
#pragma unroll
        for (int u = 0; u < 2; ++u) {
            float a0 = A[2*u], a1 = A[2*u+1];
            float b0 = B[2*u], b1 = B[2*u+1];
            float c0 = C[2*u], c1 = C[2*u+1];
            float d0 = D[2*u], d1 = D[2*u+1];
            // w stage
            float s0 = a0 + a1, q0 = a0 - a1;   // (t0,h0)
            float s1 = b0 + b1, q1 = b0 - b1;   // (t0,h1)
            float s2 = c0 + c1, q2 = c0 - c1;   // (t1,h0)
            float s3 = d0 + d1, q3 = d0 - d1;   // (t1,h1)
            // h stage
            float hse0 = s0 + s1, hde0 = s0 - s1;
            float hsd0 = q0 + q1, hdd0 = q0 - q1;
            float hse1 = s2 + s3, hde1 = s2 - s3;
            float hsd1 = q2 + q3, hdd1 = q2 - q3;
            // t stage; s = st*4 + sh*2 + sw
            o[0][q][u] = (hse0 + hse1) * SCALE_;
            o[1][q][u] = (hsd0 + hsd1) * SCALE_;
            o[2][q][u] = (hde0 + hde1) * SCALE_;
            o[3][q][u] = (hdd0 + hdd1) * SCALE_;
            o[4][q][u] = (hse0 - hse1) * SCALE_;
            o[5][q][u] = (hsd0 - hsd1) * SCALE_;
            o[6][q][u] = (hde0 - hde1) * SCALE_;
            o[7][q][u] = (hdd0 - hdd1) * SCALE_;
        }
    }

    // out channel = s*C + c
    const size_t HpWp = (size_t)Hp_ * Wp_;
    const size_t SBSTRIDE = (size_t)C_ * Tp_ * HpWp;
    float* op = out + ((size_t)(b * 8 * C_ + c) * Tp_ + i) * HpWp
              + (size_t)j * Wp_ + 2 * lane;

#pragma unroll
    for (int s = 0; s < 8; ++s) {
        float* ps = op + (size_t)s * SBSTRIDE;
        __builtin_nontemporal_store(o[s][0], (v2f*)ps);
        __builtin_nontemporal_store(o[s][1], (v2f*)(ps + 128));
    }
}

extern "C" void kernel_launch(void* const* d_in, const int* in_sizes, int n_in,
                              void* d_out, int out_size, void* d_ws, size_t ws_size,
                              hipStream_t stream) {
    const float* x = (const float*)d_in[0];
    float* out = (float*)d_out;
    dim3 grid(Hp_ / 4, Tp_, B_ * C_);   // (64, 17, 6) = 6528 blocks x 256 threads
    haar3d_kernel<<<grid, 256, 0, stream>>>(x, out);
}